// Round 3
// baseline (2159.321 us; speedup 1.0000x reference)
//
#include <hip/hip_runtime.h>
#include <hip/hip_bf16.h>

#define B_  2
#define S_  2048
#define D_  2048
#define H_  16
#define DK_ 128
#define M_  (B_*S_)   // 4096

typedef unsigned short u16;
typedef short bf16x8 __attribute__((ext_vector_type(8)));
typedef float f32x4  __attribute__((ext_vector_type(4)));

#define NEG_BIG (-1.0e30f)

// round-to-nearest-even fp32 -> bf16 (finite inputs)
__device__ __forceinline__ u16 f2bf(float f){
    unsigned int u = __float_as_uint(f);
    unsigned int r = (u + 0x7fffu + ((u >> 16) & 1u)) >> 16;
    return (u16)r;
}

// load 8 consecutive f32, convert to 8 bf16 packed in a uint4
__device__ __forceinline__ uint4 cvt8(const float* p){
    float4 a = *(const float4*)p;
    float4 b = *(const float4*)(p + 4);
    uint4 r;
    r.x = ((unsigned int)f2bf(a.y) << 16) | (unsigned int)f2bf(a.x);
    r.y = ((unsigned int)f2bf(a.w) << 16) | (unsigned int)f2bf(a.z);
    r.z = ((unsigned int)f2bf(b.y) << 16) | (unsigned int)f2bf(b.x);
    r.w = ((unsigned int)f2bf(b.w) << 16) | (unsigned int)f2bf(b.z);
    return r;
}

// unpack 8 bf16 (uint4) -> 8 f32
__device__ __forceinline__ void unpack8(const uint4 v, float* f){
    f[0]=__uint_as_float(v.x<<16); f[1]=__uint_as_float(v.x&0xffff0000u);
    f[2]=__uint_as_float(v.y<<16); f[3]=__uint_as_float(v.y&0xffff0000u);
    f[4]=__uint_as_float(v.z<<16); f[5]=__uint_as_float(v.z&0xffff0000u);
    f[6]=__uint_as_float(v.w<<16); f[7]=__uint_as_float(v.w&0xffff0000u);
}

// C = A * W^T with fp32 accumulation, bf16 MFMA internally.
// MODE 0: A = x  (f32, row-major [4096,2048]); W = wq/wk/wv (f32 [2048,2048], picked
//         by blockIdx.z); C -> bf16 in [B,H,S,dk] layout.
// MODE 1: A = attention O (bf16, [B,H,S,dk] layout, remapped read); W = wo (f32);
//         C -> f32 plain [M,N] (d_out).
template<int MODE>
__global__ __launch_bounds__(256) void gemm_bt(
    const void* __restrict__ Av,
    const float* __restrict__ W0, const float* __restrict__ W1, const float* __restrict__ W2,
    void* __restrict__ C0, void* __restrict__ C1, void* __restrict__ C2)
{
    __shared__ u16 As[128*40];   // 32-wide K tile, rows padded to 40 (80 B, 16B-aligned)
    __shared__ u16 Bs[128*40];

    const int tid  = threadIdx.x;
    const int lane = tid & 63;
    const int w    = tid >> 6;
    const int quad = lane >> 4;
    const int l15  = lane & 15;
    const int blockN = blockIdx.x * 128;
    const int blockM = blockIdx.y * 128;

    const float* Wm; void* Cm;
    if (MODE == 0) {
        Wm = (blockIdx.z == 0) ? W0 : (blockIdx.z == 1) ? W1 : W2;
        Cm = (blockIdx.z == 0) ? C0 : (blockIdx.z == 1) ? C1 : C2;
    } else { Wm = W0; Cm = C0; }

    const int waveM = (w & 1) * 64;
    const int waveN = (w >> 1) * 64;

    f32x4 acc[16];
    const f32x4 zero = {0.f, 0.f, 0.f, 0.f};
    #pragma unroll
    for (int i = 0; i < 16; ++i) acc[i] = zero;

    for (int k0 = 0; k0 < 2048; k0 += 32){
        __syncthreads();
        #pragma unroll
        for (int it = 0; it < 2; ++it){
            int cc  = tid + it*256;          // 0..511 chunk id
            int row = cc >> 2;               // 0..127
            int ch  = cc & 3;                // 8-elem chunk within 32-wide k
            int kb  = k0 + ch*8;
            uint4 va;
            if (MODE == 0){
                va = cvt8(&((const float*)Av)[(size_t)(blockM+row)*2048 + kb]);
            } else {
                int g = blockM + row;
                int b = g >> 11, s = g & 2047;
                int h = kb >> 7, kk = kb & 127;
                va = *(const uint4*)&((const u16*)Av)[(((size_t)(b*H_ + h))*S_ + s)*DK_ + kk];
            }
            uint4 vb = cvt8(&Wm[(size_t)(blockN+row)*2048 + kb]);
            *(uint4*)&As[row*40 + ch*8] = va;
            *(uint4*)&Bs[row*40 + ch*8] = vb;
        }
        __syncthreads();

        bf16x8 af[4], bfv[4];
        #pragma unroll
        for (int mi = 0; mi < 4; ++mi)
            af[mi]  = *(const bf16x8*)&As[(waveM + mi*16 + l15)*40 + quad*8];
        #pragma unroll
        for (int ni = 0; ni < 4; ++ni)
            bfv[ni] = *(const bf16x8*)&Bs[(waveN + ni*16 + l15)*40 + quad*8];
        #pragma unroll
        for (int mi = 0; mi < 4; ++mi)
            #pragma unroll
            for (int ni = 0; ni < 4; ++ni)
                acc[mi*4+ni] = __builtin_amdgcn_mfma_f32_16x16x32_bf16(
                                   af[mi], bfv[ni], acc[mi*4+ni], 0, 0, 0);
    }

    // epilogue: C[row][col], row=(lane>>4)*4+reg, col=lane&15 (verified m89/m91 layout)
    #pragma unroll
    for (int mi = 0; mi < 4; ++mi){
        #pragma unroll
        for (int ni = 0; ni < 4; ++ni){
            #pragma unroll
            for (int r = 0; r < 4; ++r){
                float v = acc[mi*4+ni][r];
                int row = blockM + waveM + mi*16 + quad*4 + r;
                int col = blockN + waveN + ni*16 + l15;
                if (MODE == 0){
                    int b = row >> 11, s = row & 2047;
                    int h = col >> 7,  kk = col & 127;
                    ((u16*)Cm)[(((size_t)(b*H_ + h))*S_ + s)*DK_ + kk] = f2bf(v);
                } else {
                    ((float*)Cm)[(size_t)row*2048 + col] = v;
                }
            }
        }
    }
}

// In-place interleaved-pair RoPE on Q (blockIdx.y=0) and K (blockIdx.y=1), bf16 [B*H, S, 128]
__global__ __launch_bounds__(256) void rope_kernel(u16* __restrict__ Q, u16* __restrict__ K)
{
    u16* T = blockIdx.y ? K : Q;
    int t  = blockIdx.x * 256 + threadIdx.x;      // 0 .. 32*2048*16-1
    int i0 = (t & 15) * 4;                        // first pair index (of 64)
    int s  = (t >> 4) & 2047;
    size_t base = ((size_t)(t >> 4)) * 128 + (size_t)i0 * 2;
    uint4 v = *(const uint4*)&T[base];
    float f[8]; unpack8(v, f);
    const float nl2t = -13.287712379549449f / 64.0f;  // -log2(10000)/64
    float sf = (float)s;
    unsigned int out[4];
    #pragma unroll
    for (int p = 0; p < 4; ++p){
        float inv = exp2f((float)(i0 + p) * nl2t);
        float ang = sf * inv;
        float sn, cn;
        sincosf(ang, &sn, &cn);
        float e0 = f[2*p], e1 = f[2*p+1];
        float r0 = e0*cn - e1*sn;
        float r1 = e1*cn + e0*sn;
        out[p] = ((unsigned int)f2bf(r1) << 16) | (unsigned int)f2bf(r0);
    }
    uint4 ov; ov.x = out[0]; ov.y = out[1]; ov.z = out[2]; ov.w = out[3];
    *(uint4*)&T[base] = ov;
}

// Flash attention, vector fp32 online softmax. One block per (q-block of 64, bh).
// Thread (r = tid>>2, c = tid&3): keys j === c (mod 4) for scores; output dims [c*32, c*32+32).
// NOTE: O aliases Q (each block writes only its own Q rows, staged to LDS up front).
__global__ __launch_bounds__(256) void attn_kernel(
    const u16* Q, const u16* __restrict__ K,
    const u16* __restrict__ V, u16* O)
{
    __shared__ u16 Qs[64*136];   // rows padded to 136 (272 B) -> conflict-free
    __shared__ u16 Ks[64*136];
    __shared__ u16 Vs[64*136];

    const int tid  = threadIdx.x;
    const int qb   = blockIdx.x;
    const int bh   = blockIdx.y;
    const int r    = tid >> 2;
    const int c    = tid & 3;
    const int lane = tid & 63;
    const size_t bhbase = (size_t)bh * S_ * DK_;

    // stage Q tile once
    #pragma unroll
    for (int it = 0; it < 4; ++it){
        int cc = tid + it*256;
        int row = cc >> 4, col8 = (cc & 15) * 8;
        *(uint4*)&Qs[row*136 + col8] =
            *(const uint4*)&Q[bhbase + (size_t)(qb*64 + row)*128 + col8];
    }

    float m_i = NEG_BIG, l_i = 0.f;
    float o[32];
    #pragma unroll
    for (int e = 0; e < 32; ++e) o[e] = 0.f;

    const float scale = 0.08838834764831845f;   // 1/sqrt(128)
    const int qg = qb*64 + r;

    for (int kb = 0; kb <= qb; ++kb){
        __syncthreads();
        #pragma unroll
        for (int it = 0; it < 4; ++it){
            int cc = tid + it*256;
            int row = cc >> 4, col8 = (cc & 15) * 8;
            size_t g = bhbase + (size_t)(kb*64 + row)*128 + col8;
            *(uint4*)&Ks[row*136 + col8] = *(const uint4*)&K[g];
            *(uint4*)&Vs[row*136 + col8] = *(const uint4*)&V[g];
        }
        __syncthreads();

        // scores for this thread's 16 keys (j = 4m + c)
        float sc[16];
        #pragma unroll
        for (int m = 0; m < 16; ++m) sc[m] = 0.f;
        #pragma unroll 4
        for (int d8 = 0; d8 < 16; ++d8){
            float qf[8]; unpack8(*(const uint4*)&Qs[r*136 + d8*8], qf);
            #pragma unroll
            for (int m = 0; m < 16; ++m){
                float kf[8]; unpack8(*(const uint4*)&Ks[(m*4 + c)*136 + d8*8], kf);
                #pragma unroll
                for (int e = 0; e < 8; ++e) sc[m] += qf[e]*kf[e];
            }
        }
        #pragma unroll
        for (int m = 0; m < 16; ++m){
            int jg = kb*64 + m*4 + c;
            sc[m] = (jg <= qg) ? sc[m]*scale : NEG_BIG;
        }

        float mloc = sc[0];
        #pragma unroll
        for (int m = 1; m < 16; ++m) mloc = fmaxf(mloc, sc[m]);
        mloc = fmaxf(mloc, __shfl_xor(mloc, 1, 64));
        mloc = fmaxf(mloc, __shfl_xor(mloc, 2, 64));
        float mnew  = fmaxf(m_i, mloc);          // always a real finite score (key kb*64 valid)
        float alpha = __expf(m_i - mnew);        // first iter: exp(-1e30)=0, inf-free
        float psum = 0.f;
        #pragma unroll
        for (int m = 0; m < 16; ++m){ float p = __expf(sc[m] - mnew); sc[m] = p; psum += p; }
        psum += __shfl_xor(psum, 1, 64);
        psum += __shfl_xor(psum, 2, 64);
        l_i = l_i*alpha + psum;
        #pragma unroll
        for (int e = 0; e < 32; ++e) o[e] *= alpha;

        // PV: broadcast p across the 4 lanes of each row
        #pragma unroll 4
        for (int m = 0; m < 16; ++m){
            #pragma unroll
            for (int c2 = 0; c2 < 4; ++c2){
                float pv = __shfl(sc[m], (lane & ~3) | c2, 64);
                const u16* vrow = &Vs[(m*4 + c2)*136 + c*32];
                #pragma unroll
                for (int q8 = 0; q8 < 4; ++q8){
                    float vf[8]; unpack8(*(const uint4*)&vrow[q8*8], vf);
                    #pragma unroll
                    for (int e = 0; e < 8; ++e) o[q8*8 + e] += pv*vf[e];
                }
            }
        }
        m_i = mnew;
    }

    float invl = 1.f / l_i;
    size_t ob = bhbase + (size_t)(qb*64 + r)*128 + c*32;
    #pragma unroll
    for (int e = 0; e < 16; ++e){
        unsigned int u = ((unsigned int)f2bf(o[2*e+1]*invl) << 16)
                       |  (unsigned int)f2bf(o[2*e]*invl);
        *(unsigned int*)&O[ob + 2*e] = u;
    }
}

extern "C" void kernel_launch(void* const* d_in, const int* in_sizes, int n_in,
                              void* d_out, int out_size, void* d_ws, size_t ws_size,
                              hipStream_t stream)
{
    // Reference dtypes: ALL inputs f32, output f32. bf16 used only internally.
    const float* x  = (const float*)d_in[0];
    const float* wq = (const float*)d_in[1];
    const float* wk = (const float*)d_in[2];
    const float* wv = (const float*)d_in[3];
    const float* wo = (const float*)d_in[4];
    float* out = (float*)d_out;

    // Scratch plan (ws use = 16 MiB only):
    //   Q (bf16, 16 MiB)        -> ws        (attention O overwrites it)
    //   V (bf16, 16 MiB)        -> d_out bytes [0,   16 MiB)
    //   K (bf16, 16 MiB)        -> d_out bytes [16 MiB, 32 MiB)
    // d_out is 8388608 f32 = 32 MiB; K and V are dead before the final f32 GEMM
    // overwrites the full buffer.
    const size_t NT = (size_t)B_ * H_ * S_ * DK_;   // 8388608 bf16 elems = 16 MiB
    u16* Qw = (u16*)d_ws;
    u16* Vd = (u16*)d_out;
    u16* Kw = (u16*)d_out + NT;
    u16* Ow = Qw;

    // 1) fused QKV projection (3 BT-GEMMs via blockIdx.z), f32 in -> bf16 [B,H,S,dk]
    gemm_bt<0><<<dim3(16, 32, 3), 256, 0, stream>>>(x, wq, wk, wv, Qw, Kw, Vd);
    // 2) RoPE in-place on Q and K
    rope_kernel<<<dim3(4096, 2), 256, 0, stream>>>(Qw, Kw);
    // 3) causal flash attention -> O (into Q buffer)
    attn_kernel<<<dim3(32, 32), 256, 0, stream>>>(Qw, Kw, Vd, Ow);
    // 4) output projection: out = Oflat * wo^T -> f32 [B*S, D] (overwrites K,V)
    gemm_bt<1><<<dim3(16, 32, 1), 256, 0, stream>>>(Ow, wo, nullptr, nullptr,
                                                    out, nullptr, nullptr);
}

// Round 4
// 583.007 us; speedup vs baseline: 3.7038x; 3.7038x over previous
//
#include <hip/hip_runtime.h>
#include <hip/hip_bf16.h>

#define B_  2
#define S_  2048
#define D_  2048
#define H_  16
#define DK_ 128
#define M_  (B_*S_)   // 4096

typedef unsigned short u16;
typedef short bf16x8 __attribute__((ext_vector_type(8)));
typedef float f32x4  __attribute__((ext_vector_type(4)));

#define NEG_BIG (-1.0e30f)

// round-to-nearest-even fp32 -> bf16 (finite inputs)
__device__ __forceinline__ u16 f2bf(float f){
    unsigned int u = __float_as_uint(f);
    unsigned int r = (u + 0x7fffu + ((u >> 16) & 1u)) >> 16;
    return (u16)r;
}

// load 8 consecutive f32, convert to 8 bf16 packed in a uint4
__device__ __forceinline__ uint4 cvt8(const float* p){
    float4 a = *(const float4*)p;
    float4 b = *(const float4*)(p + 4);
    uint4 r;
    r.x = ((unsigned int)f2bf(a.y) << 16) | (unsigned int)f2bf(a.x);
    r.y = ((unsigned int)f2bf(a.w) << 16) | (unsigned int)f2bf(a.z);
    r.z = ((unsigned int)f2bf(b.y) << 16) | (unsigned int)f2bf(b.x);
    r.w = ((unsigned int)f2bf(b.w) << 16) | (unsigned int)f2bf(b.z);
    return r;
}

// unpack 8 bf16 (uint4) -> 8 f32
__device__ __forceinline__ void unpack8(const uint4 v, float* f){
    f[0]=__uint_as_float(v.x<<16); f[1]=__uint_as_float(v.x&0xffff0000u);
    f[2]=__uint_as_float(v.y<<16); f[3]=__uint_as_float(v.y&0xffff0000u);
    f[4]=__uint_as_float(v.z<<16); f[5]=__uint_as_float(v.z&0xffff0000u);
    f[6]=__uint_as_float(v.w<<16); f[7]=__uint_as_float(v.w&0xffff0000u);
}

// C[m][n] = sum_d A[m][d] * W[n][d]  (both operands row-major, k-major), fp32 accum.
// MODE 0: A = x (f32 [4096,2048]); W = wq/wk picked by blockIdx.z; C -> bf16 [B,H,S,dk].
// MODE 2: A = wv (f32 [2048,2048], m = h*128+kk); W = x (f32, n = b*2048+s);
//         C -> bf16 V^T layout [B,H,dk,S].
// MODE 1: A = attention O (bf16, [B,H,S,dk] remapped read); W = wo (f32); C -> f32 [M,N].
template<int MODE>
__global__ __launch_bounds__(256) void gemm_bt(
    const void* __restrict__ Av,
    const float* __restrict__ W0, const float* __restrict__ W1,
    void* __restrict__ C0, void* __restrict__ C1)
{
    __shared__ u16 As[128*40];   // 32-wide K tile, rows padded to 40 (80 B, 16B-aligned)
    __shared__ u16 Bs[128*40];

    const int tid  = threadIdx.x;
    const int lane = tid & 63;
    const int w    = tid >> 6;
    const int quad = lane >> 4;
    const int l15  = lane & 15;
    const int blockN = blockIdx.x * 128;
    const int blockM = blockIdx.y * 128;

    const float* Wm; void* Cm;
    if (MODE == 0){ Wm = blockIdx.z ? W1 : W0; Cm = blockIdx.z ? C1 : C0; }
    else          { Wm = W0; Cm = C0; }

    const int waveM = (w & 1) * 64;
    const int waveN = (w >> 1) * 64;

    f32x4 acc[16];
    const f32x4 zero = {0.f, 0.f, 0.f, 0.f};
    #pragma unroll
    for (int i = 0; i < 16; ++i) acc[i] = zero;

    for (int k0 = 0; k0 < 2048; k0 += 32){
        __syncthreads();
        #pragma unroll
        for (int it = 0; it < 2; ++it){
            int cc  = tid + it*256;          // 0..511 chunk id
            int row = cc >> 2;               // 0..127
            int ch  = cc & 3;                // 8-elem chunk within 32-wide k
            int kb  = k0 + ch*8;
            uint4 va;
            if (MODE == 1){
                int g = blockM + row;
                int b = g >> 11, s2 = g & 2047;
                int h = kb >> 7, kk = kb & 127;
                va = *(const uint4*)&((const u16*)Av)[(((size_t)(b*H_ + h))*S_ + s2)*DK_ + kk];
            } else {
                va = cvt8(&((const float*)Av)[(size_t)(blockM+row)*2048 + kb]);
            }
            uint4 vb = cvt8(&Wm[(size_t)(blockN+row)*2048 + kb]);
            *(uint4*)&As[row*40 + ch*8] = va;
            *(uint4*)&Bs[row*40 + ch*8] = vb;
        }
        __syncthreads();

        bf16x8 af[4], bfv[4];
        #pragma unroll
        for (int mi = 0; mi < 4; ++mi)
            af[mi]  = *(const bf16x8*)&As[(waveM + mi*16 + l15)*40 + quad*8];
        #pragma unroll
        for (int ni = 0; ni < 4; ++ni)
            bfv[ni] = *(const bf16x8*)&Bs[(waveN + ni*16 + l15)*40 + quad*8];
        #pragma unroll
        for (int mi = 0; mi < 4; ++mi)
            #pragma unroll
            for (int ni = 0; ni < 4; ++ni)
                acc[mi*4+ni] = __builtin_amdgcn_mfma_f32_16x16x32_bf16(
                                   af[mi], bfv[ni], acc[mi*4+ni], 0, 0, 0);
    }

    // epilogue: C[row][col], row=(lane>>4)*4+reg, col=lane&15 (HW-verified layout)
    #pragma unroll
    for (int mi = 0; mi < 4; ++mi){
        #pragma unroll
        for (int ni = 0; ni < 4; ++ni){
            #pragma unroll
            for (int r = 0; r < 4; ++r){
                float v = acc[mi*4+ni][r];
                int row = blockM + waveM + mi*16 + quad*4 + r;
                int col = blockN + waveN + ni*16 + l15;
                if (MODE == 0){
                    int b = row >> 11, s2 = row & 2047;
                    int h = col >> 7,  kk = col & 127;
                    ((u16*)Cm)[(((size_t)(b*H_ + h))*S_ + s2)*DK_ + kk] = f2bf(v);
                } else if (MODE == 2){
                    int h = row >> 7,  kk = row & 127;
                    int b = col >> 11, s2 = col & 2047;
                    ((u16*)Cm)[(((size_t)(b*H_ + h))*DK_ + kk)*S_ + s2] = f2bf(v);
                } else {
                    ((float*)Cm)[(size_t)row*2048 + col] = v;
                }
            }
        }
    }
}

// In-place interleaved-pair RoPE on Q (blockIdx.y=0) and K (blockIdx.y=1), bf16 [B*H, S, 128].
// Q is additionally pre-scaled by 1/sqrt(dk) (folds the softmax scale into the QK^T MFMA).
__global__ __launch_bounds__(256) void rope_kernel(u16* __restrict__ Q, u16* __restrict__ K)
{
    u16* T = blockIdx.y ? K : Q;
    const float osc = blockIdx.y ? 1.0f : 0.08838834764831845f;  // 1/sqrt(128)
    int t  = blockIdx.x * 256 + threadIdx.x;      // 0 .. 32*2048*16-1
    int i0 = (t & 15) * 4;                        // first pair index (of 64)
    int s  = (t >> 4) & 2047;
    size_t base = ((size_t)(t >> 4)) * 128 + (size_t)i0 * 2;
    uint4 v = *(const uint4*)&T[base];
    float f[8]; unpack8(v, f);
    const float nl2t = -13.287712379549449f / 64.0f;  // -log2(10000)/64
    float sf = (float)s;
    unsigned int out[4];
    #pragma unroll
    for (int p = 0; p < 4; ++p){
        float inv = exp2f((float)(i0 + p) * nl2t);
        float ang = sf * inv;
        float sn, cn;
        sincosf(ang, &sn, &cn);
        float e0 = f[2*p], e1 = f[2*p+1];
        float r0 = (e0*cn - e1*sn) * osc;
        float r1 = (e1*cn + e0*sn) * osc;
        out[p] = ((unsigned int)f2bf(r1) << 16) | (unsigned int)f2bf(r0);
    }
    uint4 ov; ov.x = out[0]; ov.y = out[1]; ov.z = out[2]; ov.w = out[3];
    *(uint4*)&T[base] = ov;
}

// MFMA flash attention. Block = 4 waves, Q-tile 128 (wave owns 32 q), K-tile 64/iter.
// Q pre-scaled by 1/sqrt(dk). V supplied TRANSPOSED: VT [B,H,dk,S].
// grid.x = bh (fast axis -> same-XCD L2 reuse of K/VT), grid.y reversed qb (heavy first).
// O aliases Q: block writes only its own q rows, Q frags read once at kernel start.
__global__ __launch_bounds__(256) void attn_mfma(
    const u16* Q, const u16* __restrict__ K,
    const u16* __restrict__ VT, u16* O)
{
    __shared__ u16 Ks[64*136];     // K tile  [j][dk], +8 pad
    __shared__ u16 Vs[128*72];     // VT tile [v][j],  +8 pad
    __shared__ u16 Ps[4][32*72];   // per-wave P round-trip [q][j], +8 pad

    const int tid  = threadIdx.x;
    const int bh   = blockIdx.x;
    const int qb   = (int)gridDim.y - 1 - (int)blockIdx.y;
    const int w    = tid >> 6;
    const int lane = tid & 63;
    const int quad = lane >> 4;
    const int l15  = lane & 15;
    const size_t qkb = (size_t)bh * S_ * DK_;   // base for Q, K, O, and VT (same count)

    const int qw = qb*128 + w*32;               // wave's first q row

    // Q A-frags, read once from global (row = lane&15, k-chunk = quad*8)
    bf16x8 aq[2][4];
    #pragma unroll
    for (int mt = 0; mt < 2; ++mt){
        const u16* qp = &Q[qkb + (size_t)(qw + mt*16 + l15)*128 + quad*8];
        #pragma unroll
        for (int kt = 0; kt < 4; ++kt)
            aq[mt][kt] = *(const bf16x8*)(qp + kt*32);
    }

    f32x4 oa[2][8];
    float m_i[2][4], l_i[2][4];
    #pragma unroll
    for (int mt = 0; mt < 2; ++mt){
        #pragma unroll
        for (int vt = 0; vt < 8; ++vt) oa[mt][vt] = (f32x4){0.f,0.f,0.f,0.f};
        #pragma unroll
        for (int rr = 0; rr < 4; ++rr){ m_i[mt][rr] = NEG_BIG; l_i[mt][rr] = 0.f; }
    }

    const int nkb = 2*qb + 2;
    for (int kb = 0; kb < nkb; ++kb){
        __syncthreads();
        #pragma unroll
        for (int it = 0; it < 4; ++it){              // K: 64 rows x 128
            int cc = tid + it*256;
            int row = cc >> 4, c8 = (cc & 15)*8;
            *(uint4*)&Ks[row*136 + c8] =
                *(const uint4*)&K[qkb + (size_t)(kb*64 + row)*128 + c8];
        }
        #pragma unroll
        for (int it = 0; it < 4; ++it){              // VT: 128 rows x 64
            int cc = tid + it*256;
            int row = cc >> 3, c8 = (cc & 7)*8;
            *(uint4*)&Vs[row*72 + c8] =
                *(const uint4*)&VT[qkb + (size_t)row*S_ + kb*64 + c8];
        }
        __syncthreads();

        if (kb*64 > qw + 31) continue;   // wave-uniform: all of this wave's rows masked

        // S = Q K^T  (32q x 64j per wave)
        f32x4 s[2][4];
        #pragma unroll
        for (int nt = 0; nt < 4; ++nt){
            bf16x8 bk[4];
            #pragma unroll
            for (int kt = 0; kt < 4; ++kt)
                bk[kt] = *(const bf16x8*)&Ks[(nt*16 + l15)*136 + kt*32 + quad*8];
            #pragma unroll
            for (int mt = 0; mt < 2; ++mt){
                f32x4 a = (f32x4){0.f,0.f,0.f,0.f};
                #pragma unroll
                for (int kt = 0; kt < 4; ++kt)
                    a = __builtin_amdgcn_mfma_f32_16x16x32_bf16(aq[mt][kt], bk[kt], a, 0,0,0);
                s[mt][nt] = a;
            }
        }

        // causal mask (only diagonal tiles need it)
        if (kb*64 + 63 > qw){
            #pragma unroll
            for (int mt = 0; mt < 2; ++mt)
              #pragma unroll
              for (int nt = 0; nt < 4; ++nt)
                #pragma unroll
                for (int rr = 0; rr < 4; ++rr){
                    int qg = qw + mt*16 + quad*4 + rr;
                    int jg = kb*64 + nt*16 + l15;
                    if (jg > qg) s[mt][nt][rr] = NEG_BIG;
                }
        }

        // online softmax per q-row (C rows == softmax rows -> alpha applies in-register)
        #pragma unroll
        for (int mt = 0; mt < 2; ++mt){
            #pragma unroll
            for (int rr = 0; rr < 4; ++rr){
                float mx = fmaxf(fmaxf(s[mt][0][rr], s[mt][1][rr]),
                                 fmaxf(s[mt][2][rr], s[mt][3][rr]));
                mx = fmaxf(mx, __shfl_xor(mx, 1, 64));
                mx = fmaxf(mx, __shfl_xor(mx, 2, 64));
                mx = fmaxf(mx, __shfl_xor(mx, 4, 64));
                mx = fmaxf(mx, __shfl_xor(mx, 8, 64));
                float mn = fmaxf(m_i[mt][rr], mx);
                float al = __expf(m_i[mt][rr] - mn);
                float ps = 0.f;
                #pragma unroll
                for (int nt = 0; nt < 4; ++nt){
                    float p = __expf(s[mt][nt][rr] - mn);
                    s[mt][nt][rr] = p; ps += p;
                }
                ps += __shfl_xor(ps, 1, 64);
                ps += __shfl_xor(ps, 2, 64);
                ps += __shfl_xor(ps, 4, 64);
                ps += __shfl_xor(ps, 8, 64);
                l_i[mt][rr] = l_i[mt][rr]*al + ps;
                m_i[mt][rr] = mn;
                #pragma unroll
                for (int vt = 0; vt < 8; ++vt) oa[mt][vt][rr] *= al;
            }
        }

        // P: C-layout -> LDS (bf16) -> A-frags (per-wave private region, no barrier)
        u16* pw = Ps[w];
        #pragma unroll
        for (int mt = 0; mt < 2; ++mt)
          #pragma unroll
          for (int nt = 0; nt < 4; ++nt)
            #pragma unroll
            for (int rr = 0; rr < 4; ++rr)
                pw[(mt*16 + quad*4 + rr)*72 + nt*16 + l15] = f2bf(s[mt][nt][rr]);

        bf16x8 pa[2][2];
        #pragma unroll
        for (int mt = 0; mt < 2; ++mt)
          #pragma unroll
          for (int kt = 0; kt < 2; ++kt)
            pa[mt][kt] = *(const bf16x8*)&pw[(mt*16 + l15)*72 + kt*32 + quad*8];

        // O += P V  (B-frag rows = v dims from VT tile, k = j)
        #pragma unroll
        for (int vt = 0; vt < 8; ++vt){
            bf16x8 bv[2];
            #pragma unroll
            for (int kt = 0; kt < 2; ++kt)
                bv[kt] = *(const bf16x8*)&Vs[(vt*16 + l15)*72 + kt*32 + quad*8];
            #pragma unroll
            for (int mt = 0; mt < 2; ++mt)
              #pragma unroll
              for (int kt = 0; kt < 2; ++kt)
                oa[mt][vt] = __builtin_amdgcn_mfma_f32_16x16x32_bf16(
                                 pa[mt][kt], bv[kt], oa[mt][vt], 0,0,0);
        }
    }

    // epilogue: normalize, write O [B,H,S,dk] bf16
    #pragma unroll
    for (int mt = 0; mt < 2; ++mt){
        #pragma unroll
        for (int rr = 0; rr < 4; ++rr){
            float inv = 1.f / l_i[mt][rr];
            int qg = qw + mt*16 + quad*4 + rr;
            #pragma unroll
            for (int vt = 0; vt < 8; ++vt)
                O[qkb + (size_t)qg*128 + vt*16 + l15] = f2bf(oa[mt][vt][rr] * inv);
        }
    }
}

extern "C" void kernel_launch(void* const* d_in, const int* in_sizes, int n_in,
                              void* d_out, int out_size, void* d_ws, size_t ws_size,
                              hipStream_t stream)
{
    const float* x  = (const float*)d_in[0];
    const float* wq = (const float*)d_in[1];
    const float* wk = (const float*)d_in[2];
    const float* wv = (const float*)d_in[3];
    const float* wo = (const float*)d_in[4];
    float* out = (float*)d_out;

    // Scratch plan (ws use = 16 MiB):
    //   Q  (bf16 [B,H,S,dk])  -> ws          (attention O overwrites it)
    //   VT (bf16 [B,H,dk,S])  -> d_out [0, 16 MiB)
    //   K  (bf16 [B,H,S,dk])  -> d_out [16 MiB, 32 MiB)
    // K/VT dead before the final f32 GEMM overwrites d_out.
    const size_t NT = (size_t)B_ * H_ * S_ * DK_;   // 8388608 elems
    u16* Qw  = (u16*)d_ws;
    u16* Vtd = (u16*)d_out;
    u16* Kw  = (u16*)d_out + NT;
    u16* Ow  = Qw;

    // 1a) Q,K projection (f32 in -> bf16 [B,H,S,dk])
    gemm_bt<0><<<dim3(16, 32, 2), 256, 0, stream>>>(x, wq, wk, Qw, Kw);
    // 1b) V projection, transposed output (bf16 [B,H,dk,S]): m = wv rows, n = x rows
    gemm_bt<2><<<dim3(32, 16, 1), 256, 0, stream>>>(wv, x, nullptr, Vtd, nullptr);
    // 2) RoPE in-place on Q (pre-scaled by 1/sqrt(dk)) and K
    rope_kernel<<<dim3(4096, 2), 256, 0, stream>>>(Qw, Kw);
    // 3) causal MFMA flash attention -> O (into Q buffer)
    attn_mfma<<<dim3(32, 16), 256, 0, stream>>>(Qw, Kw, Vtd, Ow);
    // 4) output projection: out = Oflat * wo^T -> f32 [B*S, D]
    gemm_bt<1><<<dim3(16, 32, 1), 256, 0, stream>>>(Ow, wo, nullptr, out, nullptr);
}

// Round 5
// 454.796 us; speedup vs baseline: 4.7479x; 1.2819x over previous
//
#include <hip/hip_runtime.h>
#include <hip/hip_bf16.h>

#define B_  2
#define S_  2048
#define D_  2048
#define H_  16
#define DK_ 128
#define M_  (B_*S_)   // 4096

typedef unsigned short u16;
typedef short bf16x8 __attribute__((ext_vector_type(8)));
typedef float f32x4  __attribute__((ext_vector_type(4)));

#define NEG_BIG (-1.0e30f)

// round-to-nearest-even fp32 -> bf16 (finite inputs)
__device__ __forceinline__ u16 f2bf(float f){
    unsigned int u = __float_as_uint(f);
    unsigned int r = (u + 0x7fffu + ((u >> 16) & 1u)) >> 16;
    return (u16)r;
}

// load 8 consecutive f32, convert to 8 bf16 packed in a uint4
__device__ __forceinline__ uint4 cvt8(const float* p){
    float4 a = *(const float4*)p;
    float4 b = *(const float4*)(p + 4);
    uint4 r;
    r.x = ((unsigned int)f2bf(a.y) << 16) | (unsigned int)f2bf(a.x);
    r.y = ((unsigned int)f2bf(a.w) << 16) | (unsigned int)f2bf(a.z);
    r.z = ((unsigned int)f2bf(b.y) << 16) | (unsigned int)f2bf(b.x);
    r.w = ((unsigned int)f2bf(b.w) << 16) | (unsigned int)f2bf(b.z);
    return r;
}

// unpack 8 bf16 (uint4) -> 8 f32
__device__ __forceinline__ void unpack8(const uint4 v, float* f){
    f[0]=__uint_as_float(v.x<<16); f[1]=__uint_as_float(v.x&0xffff0000u);
    f[2]=__uint_as_float(v.y<<16); f[3]=__uint_as_float(v.y&0xffff0000u);
    f[4]=__uint_as_float(v.z<<16); f[5]=__uint_as_float(v.z&0xffff0000u);
    f[6]=__uint_as_float(v.w<<16); f[7]=__uint_as_float(v.w&0xffff0000u);
}

// async 16B global -> LDS (gfx950 global_load_lds_dwordx4). LDS dest must be
// wave-uniform base + lane*16 — caller guarantees.
__device__ __forceinline__ void async16(const void* g, void* l){
    __builtin_amdgcn_global_load_lds(
        (const __attribute__((address_space(1))) void*)g,
        (__attribute__((address_space(3))) void*)l, 16, 0, 0);
}

// ---------------- one-shot f32 -> bf16 conversion of all inputs ----------------
// chunks of 8 elems: x 1048576 | wq 524288 | wk 524288 | wv 524288 | wo 524288
__global__ __launch_bounds__(256) void cvt_all(
    const float* __restrict__ x,  const float* __restrict__ wq, const float* __restrict__ wk,
    const float* __restrict__ wv, const float* __restrict__ wo,
    u16* __restrict__ xb, u16* __restrict__ wqb, u16* __restrict__ wkb,
    u16* __restrict__ wvb, u16* __restrict__ wob)
{
    int c = blockIdx.x*256 + threadIdx.x;
    const float* src; u16* dst; int lc;
    if      (c < 1048576){ src = x;  dst = xb;  lc = c; }
    else if (c < 1572864){ src = wq; dst = wqb; lc = c - 1048576; }
    else if (c < 2097152){ src = wk; dst = wkb; lc = c - 1572864; }
    else if (c < 2621440){ src = wv; dst = wvb; lc = c - 2097152; }
    else                 { src = wo; dst = wob; lc = c - 2621440; }
    *(uint4*)&dst[(size_t)lc*8] = cvt8(&src[(size_t)lc*8]);
}

// ---------------- pure-bf16 GEMM, m97 structure ----------------
// C[m][n] = sum_d A[m][d] * W[n][d], fp32 accum, global_load_lds staging,
// unpadded 128x32 LDS tiles with XOR k-chunk swizzle (slot ch holds k-chunk ch^(row&3)).
// MODE 0: A = xb [4096,2048]; W = wqb/wkb (blockIdx.z); C -> bf16 [B,H,S,dk].
// MODE 2: A = wvb [2048,2048] (m = h*128+kk); W = xb (n = b*2048+s); C -> bf16 VT [B,H,dk,S].
// MODE 1: A = O (bf16 [B,H,S,dk], remapped read); W = wob; C -> f32 [M,N].
template<int MODE>
__global__ __launch_bounds__(256) void gemm_pure(
    const u16* __restrict__ A, const u16* __restrict__ W0, const u16* __restrict__ W1,
    void* __restrict__ C0, void* __restrict__ C1)
{
    __shared__ __align__(16) u16 As[128*32];
    __shared__ __align__(16) u16 Bs[128*32];

    const int tid  = threadIdx.x;
    const int lane = tid & 63;
    const int w    = tid >> 6;
    const int quad = lane >> 4;
    const int l15  = lane & 15;
    const int blockN = blockIdx.x * 128;
    const int blockM = blockIdx.y * 128;

    const u16* Wm; void* Cm;
    if (MODE == 0){ Wm = blockIdx.z ? W1 : W0; Cm = blockIdx.z ? (void*)C1 : (void*)C0; }
    else          { Wm = W0; Cm = C0; }

    const int waveM = (w & 1) * 64;
    const int waveN = (w >> 1) * 64;

    f32x4 acc[16];
    #pragma unroll
    for (int i = 0; i < 16; ++i) acc[i] = (f32x4){0.f,0.f,0.f,0.f};

    // per-thread staging coords (chunk cc = tid + it*256; row = cc>>2, ch = cc&3)
    for (int k0 = 0; k0 < 2048; k0 += 32){
        __syncthreads();                       // prev iter's ds_reads drained before overwrite
        #pragma unroll
        for (int it = 0; it < 2; ++it){
            int cc  = tid + it*256;
            int row = cc >> 2;
            int ch  = cc & 3;
            int kb  = k0 + (ch ^ (row & 3))*8; // XOR swizzle on the GLOBAL side
            const u16* ga;
            if (MODE == 1){
                int g = blockM + row;
                int b = g >> 11, s2 = g & 2047;
                int h = kb >> 7, kk = kb & 127;
                ga = &A[(((size_t)(b*H_ + h))*S_ + s2)*DK_ + kk];
            } else {
                ga = &A[(size_t)(blockM + row)*2048 + kb];
            }
            async16(ga, &As[cc*8]);            // LDS dest = uniform + lane*16
            async16(&Wm[(size_t)(blockN + row)*2048 + kb], &Bs[cc*8]);
        }
        __syncthreads();                       // vmcnt(0) drain: tiles visible

        bf16x8 af[4], bfv[4];
        #pragma unroll
        for (int mi = 0; mi < 4; ++mi){
            int r = waveM + mi*16 + l15;
            af[mi]  = *(const bf16x8*)&As[r*32 + (quad ^ (r & 3))*8];
        }
        #pragma unroll
        for (int ni = 0; ni < 4; ++ni){
            int r = waveN + ni*16 + l15;
            bfv[ni] = *(const bf16x8*)&Bs[r*32 + (quad ^ (r & 3))*8];
        }
        #pragma unroll
        for (int mi = 0; mi < 4; ++mi)
            #pragma unroll
            for (int ni = 0; ni < 4; ++ni)
                acc[mi*4+ni] = __builtin_amdgcn_mfma_f32_16x16x32_bf16(
                                   af[mi], bfv[ni], acc[mi*4+ni], 0, 0, 0);
    }

    // epilogue: C[row][col], row=(lane>>4)*4+reg, col=lane&15 (HW-verified layout)
    #pragma unroll
    for (int mi = 0; mi < 4; ++mi){
        #pragma unroll
        for (int ni = 0; ni < 4; ++ni){
            #pragma unroll
            for (int r = 0; r < 4; ++r){
                float v = acc[mi*4+ni][r];
                int row = blockM + waveM + mi*16 + quad*4 + r;
                int col = blockN + waveN + ni*16 + l15;
                if (MODE == 0){
                    int b = row >> 11, s2 = row & 2047;
                    int h = col >> 7,  kk = col & 127;
                    ((u16*)Cm)[(((size_t)(b*H_ + h))*S_ + s2)*DK_ + kk] = f2bf(v);
                } else if (MODE == 2){
                    int h = row >> 7,  kk = row & 127;
                    int b = col >> 11, s2 = col & 2047;
                    ((u16*)Cm)[(((size_t)(b*H_ + h))*DK_ + kk)*S_ + s2] = f2bf(v);
                } else {
                    ((float*)Cm)[(size_t)row*2048 + col] = v;
                }
            }
        }
    }
}

// ---------------- fallback mixed GEMM (round-4, validated) ----------------
template<int MODE>
__global__ __launch_bounds__(256) void gemm_bt(
    const void* __restrict__ Av,
    const float* __restrict__ W0, const float* __restrict__ W1,
    void* __restrict__ C0, void* __restrict__ C1)
{
    __shared__ u16 As[128*40];
    __shared__ u16 Bs[128*40];

    const int tid  = threadIdx.x;
    const int lane = tid & 63;
    const int w    = tid >> 6;
    const int quad = lane >> 4;
    const int l15  = lane & 15;
    const int blockN = blockIdx.x * 128;
    const int blockM = blockIdx.y * 128;

    const float* Wm; void* Cm;
    if (MODE == 0){ Wm = blockIdx.z ? W1 : W0; Cm = blockIdx.z ? (void*)C1 : (void*)C0; }
    else          { Wm = W0; Cm = C0; }

    const int waveM = (w & 1) * 64;
    const int waveN = (w >> 1) * 64;

    f32x4 acc[16];
    #pragma unroll
    for (int i = 0; i < 16; ++i) acc[i] = (f32x4){0.f,0.f,0.f,0.f};

    for (int k0 = 0; k0 < 2048; k0 += 32){
        __syncthreads();
        #pragma unroll
        for (int it = 0; it < 2; ++it){
            int cc  = tid + it*256;
            int row = cc >> 2;
            int ch  = cc & 3;
            int kb  = k0 + ch*8;
            uint4 va;
            if (MODE == 1){
                int g = blockM + row;
                int b = g >> 11, s2 = g & 2047;
                int h = kb >> 7, kk = kb & 127;
                va = *(const uint4*)&((const u16*)Av)[(((size_t)(b*H_ + h))*S_ + s2)*DK_ + kk];
            } else {
                va = cvt8(&((const float*)Av)[(size_t)(blockM+row)*2048 + kb]);
            }
            uint4 vb = cvt8(&Wm[(size_t)(blockN+row)*2048 + kb]);
            *(uint4*)&As[row*40 + ch*8] = va;
            *(uint4*)&Bs[row*40 + ch*8] = vb;
        }
        __syncthreads();

        bf16x8 af[4], bfv[4];
        #pragma unroll
        for (int mi = 0; mi < 4; ++mi)
            af[mi]  = *(const bf16x8*)&As[(waveM + mi*16 + l15)*40 + quad*8];
        #pragma unroll
        for (int ni = 0; ni < 4; ++ni)
            bfv[ni] = *(const bf16x8*)&Bs[(waveN + ni*16 + l15)*40 + quad*8];
        #pragma unroll
        for (int mi = 0; mi < 4; ++mi)
            #pragma unroll
            for (int ni = 0; ni < 4; ++ni)
                acc[mi*4+ni] = __builtin_amdgcn_mfma_f32_16x16x32_bf16(
                                   af[mi], bfv[ni], acc[mi*4+ni], 0, 0, 0);
    }

    #pragma unroll
    for (int mi = 0; mi < 4; ++mi){
        #pragma unroll
        for (int ni = 0; ni < 4; ++ni){
            #pragma unroll
            for (int r = 0; r < 4; ++r){
                float v = acc[mi*4+ni][r];
                int row = blockM + waveM + mi*16 + quad*4 + r;
                int col = blockN + waveN + ni*16 + l15;
                if (MODE == 0){
                    int b = row >> 11, s2 = row & 2047;
                    int h = col >> 7,  kk = col & 127;
                    ((u16*)Cm)[(((size_t)(b*H_ + h))*S_ + s2)*DK_ + kk] = f2bf(v);
                } else if (MODE == 2){
                    int h = row >> 7,  kk = row & 127;
                    int b = col >> 11, s2 = col & 2047;
                    ((u16*)Cm)[(((size_t)(b*H_ + h))*DK_ + kk)*S_ + s2] = f2bf(v);
                } else {
                    ((float*)Cm)[(size_t)row*2048 + col] = v;
                }
            }
        }
    }
}

// In-place interleaved-pair RoPE on Q (blockIdx.y=0, pre-scaled by 1/sqrt(dk)) and K.
__global__ __launch_bounds__(256) void rope_kernel(u16* __restrict__ Q, u16* __restrict__ K)
{
    u16* T = blockIdx.y ? K : Q;
    const float osc = blockIdx.y ? 1.0f : 0.08838834764831845f;  // 1/sqrt(128)
    int t  = blockIdx.x * 256 + threadIdx.x;
    int i0 = (t & 15) * 4;
    int s  = (t >> 4) & 2047;
    size_t base = ((size_t)(t >> 4)) * 128 + (size_t)i0 * 2;
    uint4 v = *(const uint4*)&T[base];
    float f[8]; unpack8(v, f);
    const float nl2t = -13.287712379549449f / 64.0f;  // -log2(10000)/64
    float sf = (float)s;
    unsigned int out[4];
    #pragma unroll
    for (int p = 0; p < 4; ++p){
        float inv = exp2f((float)(i0 + p) * nl2t);
        float ang = sf * inv;
        float sn, cn;
        sincosf(ang, &sn, &cn);
        float e0 = f[2*p], e1 = f[2*p+1];
        float r0 = (e0*cn - e1*sn) * osc;
        float r1 = (e1*cn + e0*sn) * osc;
        out[p] = ((unsigned int)f2bf(r1) << 16) | (unsigned int)f2bf(r0);
    }
    uint4 ov; ov.x = out[0]; ov.y = out[1]; ov.z = out[2]; ov.w = out[3];
    *(uint4*)&T[base] = ov;
}

// MFMA flash attention (round-4, validated). Q pre-scaled; V transposed [B,H,dk,S].
__global__ __launch_bounds__(256) void attn_mfma(
    const u16* Q, const u16* __restrict__ K,
    const u16* __restrict__ VT, u16* O)
{
    __shared__ u16 Ks[64*136];
    __shared__ u16 Vs[128*72];
    __shared__ u16 Ps[4][32*72];

    const int tid  = threadIdx.x;
    const int bh   = blockIdx.x;
    const int qb   = (int)gridDim.y - 1 - (int)blockIdx.y;
    const int w    = tid >> 6;
    const int lane = tid & 63;
    const int quad = lane >> 4;
    const int l15  = lane & 15;
    const size_t qkb = (size_t)bh * S_ * DK_;

    const int qw = qb*128 + w*32;

    bf16x8 aq[2][4];
    #pragma unroll
    for (int mt = 0; mt < 2; ++mt){
        const u16* qp = &Q[qkb + (size_t)(qw + mt*16 + l15)*128 + quad*8];
        #pragma unroll
        for (int kt = 0; kt < 4; ++kt)
            aq[mt][kt] = *(const bf16x8*)(qp + kt*32);
    }

    f32x4 oa[2][8];
    float m_i[2][4], l_i[2][4];
    #pragma unroll
    for (int mt = 0; mt < 2; ++mt){
        #pragma unroll
        for (int vt = 0; vt < 8; ++vt) oa[mt][vt] = (f32x4){0.f,0.f,0.f,0.f};
        #pragma unroll
        for (int rr = 0; rr < 4; ++rr){ m_i[mt][rr] = NEG_BIG; l_i[mt][rr] = 0.f; }
    }

    const int nkb = 2*qb + 2;
    for (int kb = 0; kb < nkb; ++kb){
        __syncthreads();
        #pragma unroll
        for (int it = 0; it < 4; ++it){
            int cc = tid + it*256;
            int row = cc >> 4, c8 = (cc & 15)*8;
            *(uint4*)&Ks[row*136 + c8] =
                *(const uint4*)&K[qkb + (size_t)(kb*64 + row)*128 + c8];
        }
        #pragma unroll
        for (int it = 0; it < 4; ++it){
            int cc = tid + it*256;
            int row = cc >> 3, c8 = (cc & 7)*8;
            *(uint4*)&Vs[row*72 + c8] =
                *(const uint4*)&VT[qkb + (size_t)row*S_ + kb*64 + c8];
        }
        __syncthreads();

        if (kb*64 > qw + 31) continue;

        f32x4 s[2][4];
        #pragma unroll
        for (int nt = 0; nt < 4; ++nt){
            bf16x8 bk[4];
            #pragma unroll
            for (int kt = 0; kt < 4; ++kt)
                bk[kt] = *(const bf16x8*)&Ks[(nt*16 + l15)*136 + kt*32 + quad*8];
            #pragma unroll
            for (int mt = 0; mt < 2; ++mt){
                f32x4 a = (f32x4){0.f,0.f,0.f,0.f};
                #pragma unroll
                for (int kt = 0; kt < 4; ++kt)
                    a = __builtin_amdgcn_mfma_f32_16x16x32_bf16(aq[mt][kt], bk[kt], a, 0,0,0);
                s[mt][nt] = a;
            }
        }

        if (kb*64 + 63 > qw){
            #pragma unroll
            for (int mt = 0; mt < 2; ++mt)
              #pragma unroll
              for (int nt = 0; nt < 4; ++nt)
                #pragma unroll
                for (int rr = 0; rr < 4; ++rr){
                    int qg = qw + mt*16 + quad*4 + rr;
                    int jg = kb*64 + nt*16 + l15;
                    if (jg > qg) s[mt][nt][rr] = NEG_BIG;
                }
        }

        #pragma unroll
        for (int mt = 0; mt < 2; ++mt){
            #pragma unroll
            for (int rr = 0; rr < 4; ++rr){
                float mx = fmaxf(fmaxf(s[mt][0][rr], s[mt][1][rr]),
                                 fmaxf(s[mt][2][rr], s[mt][3][rr]));
                mx = fmaxf(mx, __shfl_xor(mx, 1, 64));
                mx = fmaxf(mx, __shfl_xor(mx, 2, 64));
                mx = fmaxf(mx, __shfl_xor(mx, 4, 64));
                mx = fmaxf(mx, __shfl_xor(mx, 8, 64));
                float mn = fmaxf(m_i[mt][rr], mx);
                float al = __expf(m_i[mt][rr] - mn);
                float ps = 0.f;
                #pragma unroll
                for (int nt = 0; nt < 4; ++nt){
                    float p = __expf(s[mt][nt][rr] - mn);
                    s[mt][nt][rr] = p; ps += p;
                }
                ps += __shfl_xor(ps, 1, 64);
                ps += __shfl_xor(ps, 2, 64);
                ps += __shfl_xor(ps, 4, 64);
                ps += __shfl_xor(ps, 8, 64);
                l_i[mt][rr] = l_i[mt][rr]*al + ps;
                m_i[mt][rr] = mn;
                #pragma unroll
                for (int vt = 0; vt < 8; ++vt) oa[mt][vt][rr] *= al;
            }
        }

        u16* pw = Ps[w];
        #pragma unroll
        for (int mt = 0; mt < 2; ++mt)
          #pragma unroll
          for (int nt = 0; nt < 4; ++nt)
            #pragma unroll
            for (int rr = 0; rr < 4; ++rr)
                pw[(mt*16 + quad*4 + rr)*72 + nt*16 + l15] = f2bf(s[mt][nt][rr]);

        bf16x8 pa[2][2];
        #pragma unroll
        for (int mt = 0; mt < 2; ++mt)
          #pragma unroll
          for (int kt = 0; kt < 2; ++kt)
            pa[mt][kt] = *(const bf16x8*)&pw[(mt*16 + l15)*72 + kt*32 + quad*8];

        #pragma unroll
        for (int vt = 0; vt < 8; ++vt){
            bf16x8 bv[2];
            #pragma unroll
            for (int kt = 0; kt < 2; ++kt)
                bv[kt] = *(const bf16x8*)&Vs[(vt*16 + l15)*72 + kt*32 + quad*8];
            #pragma unroll
            for (int mt = 0; mt < 2; ++mt)
              #pragma unroll
              for (int kt = 0; kt < 2; ++kt)
                oa[mt][vt] = __builtin_amdgcn_mfma_f32_16x16x32_bf16(
                                 pa[mt][kt], bv[kt], oa[mt][vt], 0,0,0);
        }
    }

    #pragma unroll
    for (int mt = 0; mt < 2; ++mt){
        #pragma unroll
        for (int rr = 0; rr < 4; ++rr){
            float inv = 1.f / l_i[mt][rr];
            int qg = qw + mt*16 + quad*4 + rr;
            #pragma unroll
            for (int vt = 0; vt < 8; ++vt)
                O[qkb + (size_t)qg*128 + vt*16 + l15] = f2bf(oa[mt][vt][rr] * inv);
        }
    }
}

extern "C" void kernel_launch(void* const* d_in, const int* in_sizes, int n_in,
                              void* d_out, int out_size, void* d_ws, size_t ws_size,
                              hipStream_t stream)
{
    const float* x  = (const float*)d_in[0];
    const float* wq = (const float*)d_in[1];
    const float* wk = (const float*)d_in[2];
    const float* wv = (const float*)d_in[3];
    const float* wo = (const float*)d_in[4];
    float* out = (float*)d_out;

    const size_t NT = (size_t)B_ * H_ * S_ * DK_;   // 8388608 elems (16 MiB bf16)
    const size_t NW = (size_t)D_ * D_;              // 4194304 elems (8 MiB bf16)

    if (ws_size >= (size_t)50331648){
        // ---- fast path: pre-convert everything to bf16, pure-bf16 m97 GEMMs ----
        // ws  : Q[0,16M) K[16M,32M) wvb[32M,40M) wob[40M,48M)
        // dout: xb[0,16M) wqb[16M,24M) wkb[24M,32M) -> later VT[16M,32M)
        u16* Qw  = (u16*)d_ws;
        u16* Kw  = Qw + NT;
        u16* wvb = Qw + 2*NT;
        u16* wob = wvb + NW;
        u16* xb  = (u16*)d_out;
        u16* wqb = xb + NT;
        u16* wkb = wqb + NW;
        u16* VT  = xb + NT;          // overwrites wqb/wkb after QK GEMM
        u16* Ow  = Qw;               // attention output overwrites Q

        cvt_all<<<dim3(12288), 256, 0, stream>>>(x, wq, wk, wv, wo,
                                                 xb, wqb, wkb, wvb, wob);
        gemm_pure<0><<<dim3(16, 32, 2), 256, 0, stream>>>(xb, wqb, wkb, Qw, Kw);
        gemm_pure<2><<<dim3(32, 16, 1), 256, 0, stream>>>(wvb, xb, nullptr, VT, nullptr);
        rope_kernel<<<dim3(4096, 2), 256, 0, stream>>>(Qw, Kw);
        attn_mfma<<<dim3(32, 16), 256, 0, stream>>>(Qw, Kw, VT, Ow);
        gemm_pure<1><<<dim3(16, 32, 1), 256, 0, stream>>>(Ow, wob, nullptr, out, nullptr);
    } else {
        // ---- fallback: round-4 validated path (ws use = 16 MiB) ----
        u16* Qw  = (u16*)d_ws;
        u16* Vtd = (u16*)d_out;
        u16* Kw  = (u16*)d_out + NT;
        u16* Ow  = Qw;
        gemm_bt<0><<<dim3(16, 32, 2), 256, 0, stream>>>(x, wq, wk, Qw, Kw);
        gemm_bt<2><<<dim3(32, 16, 1), 256, 0, stream>>>(wv, x, nullptr, Vtd, nullptr);
        rope_kernel<<<dim3(4096, 2), 256, 0, stream>>>(Qw, Kw);
        attn_mfma<<<dim3(32, 16), 256, 0, stream>>>(Qw, Kw, Vtd, Ow);
        gemm_bt<1><<<dim3(16, 32, 1), 256, 0, stream>>>(Ow, wo, nullptr, out, nullptr);
    }
}

// Round 7
// 441.036 us; speedup vs baseline: 4.8960x; 1.0312x over previous
//
#include <hip/hip_runtime.h>
#include <hip/hip_bf16.h>

#define B_  2
#define S_  2048
#define D_  2048
#define H_  16
#define DK_ 128
#define M_  (B_*S_)   // 4096

typedef unsigned short u16;
typedef short bf16x8 __attribute__((ext_vector_type(8)));
typedef float f32x4  __attribute__((ext_vector_type(4)));

#define NEG_BIG (-1.0e30f)

// round-to-nearest-even fp32 -> bf16 (finite inputs)
__device__ __forceinline__ u16 f2bf(float f){
    unsigned int u = __float_as_uint(f);
    unsigned int r = (u + 0x7fffu + ((u >> 16) & 1u)) >> 16;
    return (u16)r;
}

// load 8 consecutive f32, convert to 8 bf16 packed in a uint4
__device__ __forceinline__ uint4 cvt8(const float* p){
    float4 a = *(const float4*)p;
    float4 b = *(const float4*)(p + 4);
    uint4 r;
    r.x = ((unsigned int)f2bf(a.y) << 16) | (unsigned int)f2bf(a.x);
    r.y = ((unsigned int)f2bf(a.w) << 16) | (unsigned int)f2bf(a.z);
    r.z = ((unsigned int)f2bf(b.y) << 16) | (unsigned int)f2bf(b.x);
    r.w = ((unsigned int)f2bf(b.w) << 16) | (unsigned int)f2bf(b.z);
    return r;
}

// unpack 8 bf16 (uint4) -> 8 f32
__device__ __forceinline__ void unpack8(const uint4 v, float* f){
    f[0]=__uint_as_float(v.x<<16); f[1]=__uint_as_float(v.x&0xffff0000u);
    f[2]=__uint_as_float(v.y<<16); f[3]=__uint_as_float(v.y&0xffff0000u);
    f[4]=__uint_as_float(v.z<<16); f[5]=__uint_as_float(v.z&0xffff0000u);
    f[6]=__uint_as_float(v.w<<16); f[7]=__uint_as_float(v.w&0xffff0000u);
}

// async 16B global -> LDS (gfx950). LDS dest must be wave-uniform base + lane*16.
__device__ __forceinline__ void async16(const void* g, void* l){
    __builtin_amdgcn_global_load_lds(
        (const __attribute__((address_space(1))) void*)g,
        (__attribute__((address_space(3))) void*)l, 16, 0, 0);
}

// ---------------- one-shot f32 -> bf16 conversion of all inputs ----------------
__global__ __launch_bounds__(256) void cvt_all(
    const float* __restrict__ x,  const float* __restrict__ wq, const float* __restrict__ wk,
    const float* __restrict__ wv, const float* __restrict__ wo,
    u16* __restrict__ xb, u16* __restrict__ wqb, u16* __restrict__ wkb,
    u16* __restrict__ wvb, u16* __restrict__ wob)
{
    int c = blockIdx.x*256 + threadIdx.x;
    const float* src; u16* dst; int lc;
    if      (c < 1048576){ src = x;  dst = xb;  lc = c; }
    else if (c < 1572864){ src = wq; dst = wqb; lc = c - 1048576; }
    else if (c < 2097152){ src = wk; dst = wkb; lc = c - 1572864; }
    else if (c < 2621440){ src = wv; dst = wvb; lc = c - 2097152; }
    else                 { src = wo; dst = wob; lc = c - 2621440; }
    *(uint4*)&dst[(size_t)lc*8] = cvt8(&src[(size_t)lc*8]);
}

// ---------------- pure-bf16 GEMM, m97 structure (validated round 5) ----------------
template<int MODE>
__global__ __launch_bounds__(256) void gemm_pure(
    const u16* __restrict__ A, const u16* __restrict__ W0, const u16* __restrict__ W1,
    void* __restrict__ C0, void* __restrict__ C1)
{
    __shared__ __align__(16) u16 As[128*32];
    __shared__ __align__(16) u16 Bs[128*32];

    const int tid  = threadIdx.x;
    const int lane = tid & 63;
    const int w    = tid >> 6;
    const int quad = lane >> 4;
    const int l15  = lane & 15;
    const int blockN = blockIdx.x * 128;
    const int blockM = blockIdx.y * 128;

    const u16* Wm; void* Cm;
    if (MODE == 0){ Wm = blockIdx.z ? W1 : W0; Cm = blockIdx.z ? (void*)C1 : (void*)C0; }
    else          { Wm = W0; Cm = C0; }

    const int waveM = (w & 1) * 64;
    const int waveN = (w >> 1) * 64;

    f32x4 acc[16];
    #pragma unroll
    for (int i = 0; i < 16; ++i) acc[i] = (f32x4){0.f,0.f,0.f,0.f};

    for (int k0 = 0; k0 < 2048; k0 += 32){
        __syncthreads();
        #pragma unroll
        for (int it = 0; it < 2; ++it){
            int cc  = tid + it*256;
            int row = cc >> 2;
            int ch  = cc & 3;
            int kb  = k0 + (ch ^ (row & 3))*8;
            const u16* ga;
            if (MODE == 1){
                int g = blockM + row;
                int b = g >> 11, s2 = g & 2047;
                int h = kb >> 7, kk = kb & 127;
                ga = &A[(((size_t)(b*H_ + h))*S_ + s2)*DK_ + kk];
            } else {
                ga = &A[(size_t)(blockM + row)*2048 + kb];
            }
            async16(ga, &As[cc*8]);
            async16(&Wm[(size_t)(blockN + row)*2048 + kb], &Bs[cc*8]);
        }
        __syncthreads();

        bf16x8 af[4], bfv[4];
        #pragma unroll
        for (int mi = 0; mi < 4; ++mi){
            int r = waveM + mi*16 + l15;
            af[mi]  = *(const bf16x8*)&As[r*32 + (quad ^ (r & 3))*8];
        }
        #pragma unroll
        for (int ni = 0; ni < 4; ++ni){
            int r = waveN + ni*16 + l15;
            bfv[ni] = *(const bf16x8*)&Bs[r*32 + (quad ^ (r & 3))*8];
        }
        #pragma unroll
        for (int mi = 0; mi < 4; ++mi)
            #pragma unroll
            for (int ni = 0; ni < 4; ++ni)
                acc[mi*4+ni] = __builtin_amdgcn_mfma_f32_16x16x32_bf16(
                                   af[mi], bfv[ni], acc[mi*4+ni], 0, 0, 0);
    }

    #pragma unroll
    for (int mi = 0; mi < 4; ++mi){
        #pragma unroll
        for (int ni = 0; ni < 4; ++ni){
            #pragma unroll
            for (int r = 0; r < 4; ++r){
                float v = acc[mi*4+ni][r];
                int row = blockM + waveM + mi*16 + quad*4 + r;
                int col = blockN + waveN + ni*16 + l15;
                if (MODE == 0){
                    int b = row >> 11, s2 = row & 2047;
                    int h = col >> 7,  kk = col & 127;
                    ((u16*)Cm)[(((size_t)(b*H_ + h))*S_ + s2)*DK_ + kk] = f2bf(v);
                } else if (MODE == 2){
                    int h = row >> 7,  kk = row & 127;
                    int b = col >> 11, s2 = col & 2047;
                    ((u16*)Cm)[(((size_t)(b*H_ + h))*DK_ + kk)*S_ + s2] = f2bf(v);
                } else {
                    ((float*)Cm)[(size_t)row*2048 + col] = v;
                }
            }
        }
    }
}

// ---------------- fallback mixed GEMM (round-4, validated) ----------------
template<int MODE>
__global__ __launch_bounds__(256) void gemm_bt(
    const void* __restrict__ Av,
    const float* __restrict__ W0, const float* __restrict__ W1,
    void* __restrict__ C0, void* __restrict__ C1)
{
    __shared__ u16 As[128*40];
    __shared__ u16 Bs[128*40];

    const int tid  = threadIdx.x;
    const int lane = tid & 63;
    const int w    = tid >> 6;
    const int quad = lane >> 4;
    const int l15  = lane & 15;
    const int blockN = blockIdx.x * 128;
    const int blockM = blockIdx.y * 128;

    const float* Wm; void* Cm;
    if (MODE == 0){ Wm = blockIdx.z ? W1 : W0; Cm = blockIdx.z ? (void*)C1 : (void*)C0; }
    else          { Wm = W0; Cm = C0; }

    const int waveM = (w & 1) * 64;
    const int waveN = (w >> 1) * 64;

    f32x4 acc[16];
    #pragma unroll
    for (int i = 0; i < 16; ++i) acc[i] = (f32x4){0.f,0.f,0.f,0.f};

    for (int k0 = 0; k0 < 2048; k0 += 32){
        __syncthreads();
        #pragma unroll
        for (int it = 0; it < 2; ++it){
            int cc  = tid + it*256;
            int row = cc >> 2;
            int ch  = cc & 3;
            int kb  = k0 + ch*8;
            uint4 va;
            if (MODE == 1){
                int g = blockM + row;
                int b = g >> 11, s2 = g & 2047;
                int h = kb >> 7, kk = kb & 127;
                va = *(const uint4*)&((const u16*)Av)[(((size_t)(b*H_ + h))*S_ + s2)*DK_ + kk];
            } else {
                va = cvt8(&((const float*)Av)[(size_t)(blockM+row)*2048 + kb]);
            }
            uint4 vb = cvt8(&Wm[(size_t)(blockN+row)*2048 + kb]);
            *(uint4*)&As[row*40 + ch*8] = va;
            *(uint4*)&Bs[row*40 + ch*8] = vb;
        }
        __syncthreads();

        bf16x8 af[4], bfv[4];
        #pragma unroll
        for (int mi = 0; mi < 4; ++mi)
            af[mi]  = *(const bf16x8*)&As[(waveM + mi*16 + l15)*40 + quad*8];
        #pragma unroll
        for (int ni = 0; ni < 4; ++ni)
            bfv[ni] = *(const bf16x8*)&Bs[(waveN + ni*16 + l15)*40 + quad*8];
        #pragma unroll
        for (int mi = 0; mi < 4; ++mi)
            #pragma unroll
            for (int ni = 0; ni < 4; ++ni)
                acc[mi*4+ni] = __builtin_amdgcn_mfma_f32_16x16x32_bf16(
                                   af[mi], bfv[ni], acc[mi*4+ni], 0, 0, 0);
    }

    #pragma unroll
    for (int mi = 0; mi < 4; ++mi){
        #pragma unroll
        for (int ni = 0; ni < 4; ++ni){
            #pragma unroll
            for (int r = 0; r < 4; ++r){
                float v = acc[mi*4+ni][r];
                int row = blockM + waveM + mi*16 + quad*4 + r;
                int col = blockN + waveN + ni*16 + l15;
                if (MODE == 0){
                    int b = row >> 11, s2 = row & 2047;
                    int h = col >> 7,  kk = col & 127;
                    ((u16*)Cm)[(((size_t)(b*H_ + h))*S_ + s2)*DK_ + kk] = f2bf(v);
                } else if (MODE == 2){
                    int h = row >> 7,  kk = row & 127;
                    int b = col >> 11, s2 = col & 2047;
                    ((u16*)Cm)[(((size_t)(b*H_ + h))*DK_ + kk)*S_ + s2] = f2bf(v);
                } else {
                    ((float*)Cm)[(size_t)row*2048 + col] = v;
                }
            }
        }
    }
}

// In-place interleaved-pair RoPE. Q (blockIdx.y=0) is pre-scaled by log2(e)/sqrt(dk)
// so attention softmax can use exp2 directly.
__global__ __launch_bounds__(256) void rope_kernel(u16* __restrict__ Q, u16* __restrict__ K)
{
    u16* T = blockIdx.y ? K : Q;
    const float osc = blockIdx.y ? 1.0f : 0.12751743f;  // log2(e)/sqrt(128)
    int t  = blockIdx.x * 256 + threadIdx.x;
    int i0 = (t & 15) * 4;
    int s  = (t >> 4) & 2047;
    size_t base = ((size_t)(t >> 4)) * 128 + (size_t)i0 * 2;
    uint4 v = *(const uint4*)&T[base];
    float f[8]; unpack8(v, f);
    const float nl2t = -13.287712379549449f / 64.0f;  // -log2(10000)/64
    float sf = (float)s;
    unsigned int out[4];
    #pragma unroll
    for (int p = 0; p < 4; ++p){
        float inv = exp2f((float)(i0 + p) * nl2t);
        float ang = sf * inv;
        float sn, cn;
        sincosf(ang, &sn, &cn);
        float e0 = f[2*p], e1 = f[2*p+1];
        float r0 = (e0*cn - e1*sn) * osc;
        float r1 = (e1*cn + e0*sn) * osc;
        out[p] = ((unsigned int)f2bf(r1) << 16) | (unsigned int)f2bf(r0);
    }
    uint4 ov; ov.x = out[0]; ov.y = out[1]; ov.z = out[2]; ov.w = out[3];
    *(uint4*)&T[base] = ov;
}

// MFMA flash attention, transposed-scores (S^T = K·Q^T).
// S^T C-layout: q = l15 (col), j = quad*4+reg (row). Softmax stats per-lane for
// q = mt*16+l15. O accumulator (PV C-layout) has rows q = quad*4+reg — so BOTH the
// running-max rescale alpha AND the final 1/l must be shuffled from lane
// (lane&48)|(quad*4+rr). (Round-6 bug: alpha was applied un-shuffled.)
__global__ __launch_bounds__(256) void attn_mfma(
    const u16* Q, const u16* __restrict__ K,
    const u16* __restrict__ VT, u16* O)
{
    __shared__ u16 Ks[64*136];     // K tile  [j][dk]
    __shared__ u16 Vs[128*72];     // VT tile [v][j]
    __shared__ u16 Ps[4][32*72];   // per-wave P [q][j]

    const int tid  = threadIdx.x;
    const int bh   = blockIdx.x;
    const int qb   = (int)gridDim.y - 1 - (int)blockIdx.y;   // heavy blocks first
    const int w    = tid >> 6;
    const int lane = tid & 63;
    const int quad = lane >> 4;
    const int l15  = lane & 15;
    const size_t qkb = (size_t)bh * S_ * DK_;

    const int qw = qb*128 + w*32;               // wave's first q row

    // Q B-frags (n = l15 = q, k = quad*8+idx), read once from global
    bf16x8 aq[2][4];
    #pragma unroll
    for (int mt = 0; mt < 2; ++mt){
        const u16* qp = &Q[qkb + (size_t)(qw + mt*16 + l15)*128 + quad*8];
        #pragma unroll
        for (int kt = 0; kt < 4; ++kt)
            aq[mt][kt] = *(const bf16x8*)(qp + kt*32);
    }

    f32x4 oa[2][8];                 // O: row q = quad*4+reg (per mt tile), col v = l15
    float m_i[2], l_i[2];           // softmax state for q = qw + mt*16 + l15
    #pragma unroll
    for (int mt = 0; mt < 2; ++mt){
        #pragma unroll
        for (int vt = 0; vt < 8; ++vt) oa[mt][vt] = (f32x4){0.f,0.f,0.f,0.f};
        m_i[mt] = NEG_BIG; l_i[mt] = 0.f;
    }

    const int nkb = 2*qb + 2;
    for (int kb = 0; kb < nkb; ++kb){
        __syncthreads();
        #pragma unroll
        for (int it = 0; it < 4; ++it){              // K: 64 rows x 128
            int cc = tid + it*256;
            int row = cc >> 4, c8 = (cc & 15)*8;
            *(uint4*)&Ks[row*136 + c8] =
                *(const uint4*)&K[qkb + (size_t)(kb*64 + row)*128 + c8];
        }
        #pragma unroll
        for (int it = 0; it < 4; ++it){              // VT: 128 rows x 64
            int cc = tid + it*256;
            int row = cc >> 3, c8 = (cc & 7)*8;
            *(uint4*)&Vs[row*72 + c8] =
                *(const uint4*)&VT[qkb + (size_t)row*S_ + kb*64 + c8];
        }
        __syncthreads();

        if (kb*64 > qw + 31) continue;   // wave-uniform; barriers already passed

        // S^T tile: s[mt][nt]: j = nt*16+quad*4+reg, q = mt*16+l15
        f32x4 s[2][4];
        #pragma unroll
        for (int nt = 0; nt < 4; ++nt){
            bf16x8 ak[4];                // A-frag: m = j = nt*16+l15, k = quad*8+idx
            #pragma unroll
            for (int kt = 0; kt < 4; ++kt)
                ak[kt] = *(const bf16x8*)&Ks[(nt*16 + l15)*136 + kt*32 + quad*8];
            #pragma unroll
            for (int mt = 0; mt < 2; ++mt){
                f32x4 a = (f32x4){0.f,0.f,0.f,0.f};
                #pragma unroll
                for (int kt = 0; kt < 4; ++kt)
                    a = __builtin_amdgcn_mfma_f32_16x16x32_bf16(ak[kt], aq[mt][kt], a, 0,0,0);
                s[mt][nt] = a;
            }
        }

        // causal mask (diagonal tiles only): j > q -> NEG_BIG
        if (kb*64 + 63 > qw){
            #pragma unroll
            for (int mt = 0; mt < 2; ++mt){
                int qg = qw + mt*16 + l15;
                #pragma unroll
                for (int nt = 0; nt < 4; ++nt)
                    #pragma unroll
                    for (int rr = 0; rr < 4; ++rr){
                        int jg = kb*64 + nt*16 + quad*4 + rr;
                        if (jg > qg) s[mt][nt][rr] = NEG_BIG;
                    }
            }
        }

        // online softmax (exp2 domain): in-lane over 16 regs, then quad reduction
        #pragma unroll
        for (int mt = 0; mt < 2; ++mt){
            float mx = s[mt][0][0];
            #pragma unroll
            for (int nt = 0; nt < 4; ++nt)
                #pragma unroll
                for (int rr = 0; rr < 4; ++rr) mx = fmaxf(mx, s[mt][nt][rr]);
            mx = fmaxf(mx, __shfl_xor(mx, 16, 64));
            mx = fmaxf(mx, __shfl_xor(mx, 32, 64));
            float mn = fmaxf(m_i[mt], mx);
            float al = exp2f(m_i[mt] - mn);
            float ps = 0.f;
            #pragma unroll
            for (int nt = 0; nt < 4; ++nt)
                #pragma unroll
                for (int rr = 0; rr < 4; ++rr){
                    float p = exp2f(s[mt][nt][rr] - mn);
                    s[mt][nt][rr] = p; ps += p;
                }
            ps += __shfl_xor(ps, 16, 64);
            ps += __shfl_xor(ps, 32, 64);
            l_i[mt] = l_i[mt]*al + ps;
            m_i[mt] = mn;

            // FIX: alpha lives in lane with l15 == q_local, but oa rows are
            // q_local = quad*4+rr -> shuffle alpha into oa's layout before applying.
            float al4[4];
            #pragma unroll
            for (int rr = 0; rr < 4; ++rr)
                al4[rr] = __shfl(al, (lane & 48) | (quad*4 + rr), 64);
            #pragma unroll
            for (int vt = 0; vt < 8; ++vt)
                #pragma unroll
                for (int rr = 0; rr < 4; ++rr) oa[mt][vt][rr] *= al4[rr];
        }

        // P store: 4 contiguous-j bf16 per (mt,nt) -> b64 writes into [q][j] layout
        u16* pw = Ps[w];
        #pragma unroll
        for (int mt = 0; mt < 2; ++mt)
          #pragma unroll
          for (int nt = 0; nt < 4; ++nt){
              uint2 pk;
              pk.x = ((unsigned int)f2bf(s[mt][nt][1]) << 16) | (unsigned int)f2bf(s[mt][nt][0]);
              pk.y = ((unsigned int)f2bf(s[mt][nt][3]) << 16) | (unsigned int)f2bf(s[mt][nt][2]);
              *(uint2*)&pw[(mt*16 + l15)*72 + nt*16 + quad*4] = pk;
          }

        // PV: A = P[q][j], B = VT[v][j]
        bf16x8 pa[2][2];
        #pragma unroll
        for (int mt = 0; mt < 2; ++mt)
          #pragma unroll
          for (int kt = 0; kt < 2; ++kt)
            pa[mt][kt] = *(const bf16x8*)&pw[(mt*16 + l15)*72 + kt*32 + quad*8];

        #pragma unroll
        for (int vt = 0; vt < 8; ++vt){
            bf16x8 bv[2];
            #pragma unroll
            for (int kt = 0; kt < 2; ++kt)
                bv[kt] = *(const bf16x8*)&Vs[(vt*16 + l15)*72 + kt*32 + quad*8];
            #pragma unroll
            for (int mt = 0; mt < 2; ++mt)
              #pragma unroll
              for (int kt = 0; kt < 2; ++kt)
                oa[mt][vt] = __builtin_amdgcn_mfma_f32_16x16x32_bf16(
                                 pa[mt][kt], bv[kt], oa[mt][vt], 0,0,0);
        }
    }

    // epilogue: normalize (1/l shuffled into oa layout, same pattern as alpha), write O
    #pragma unroll
    for (int mt = 0; mt < 2; ++mt){
        #pragma unroll
        for (int rr = 0; rr < 4; ++rr){
            float lv = __shfl(l_i[mt], (lane & 48) | (quad*4 + rr), 64);
            float inv = 1.f / lv;
            int qg = qw + mt*16 + quad*4 + rr;
            #pragma unroll
            for (int vt = 0; vt < 8; ++vt)
                O[qkb + (size_t)qg*128 + vt*16 + l15] = f2bf(oa[mt][vt][rr] * inv);
        }
    }
}

extern "C" void kernel_launch(void* const* d_in, const int* in_sizes, int n_in,
                              void* d_out, int out_size, void* d_ws, size_t ws_size,
                              hipStream_t stream)
{
    const float* x  = (const float*)d_in[0];
    const float* wq = (const float*)d_in[1];
    const float* wk = (const float*)d_in[2];
    const float* wv = (const float*)d_in[3];
    const float* wo = (const float*)d_in[4];
    float* out = (float*)d_out;

    const size_t NT = (size_t)B_ * H_ * S_ * DK_;   // 8388608 elems (16 MiB bf16)
    const size_t NW = (size_t)D_ * D_;              // 4194304 elems (8 MiB bf16)

    if (ws_size >= (size_t)50331648){
        u16* Qw  = (u16*)d_ws;
        u16* Kw  = Qw + NT;
        u16* wvb = Qw + 2*NT;
        u16* wob = wvb + NW;
        u16* xb  = (u16*)d_out;
        u16* wqb = xb + NT;
        u16* wkb = wqb + NW;
        u16* VT  = xb + NT;
        u16* Ow  = Qw;

        cvt_all<<<dim3(12288), 256, 0, stream>>>(x, wq, wk, wv, wo,
                                                 xb, wqb, wkb, wvb, wob);
        gemm_pure<0><<<dim3(16, 32, 2), 256, 0, stream>>>(xb, wqb, wkb, Qw, Kw);
        gemm_pure<2><<<dim3(32, 16, 1), 256, 0, stream>>>(wvb, xb, nullptr, VT, nullptr);
        rope_kernel<<<dim3(4096, 2), 256, 0, stream>>>(Qw, Kw);
        attn_mfma<<<dim3(32, 16), 256, 0, stream>>>(Qw, Kw, VT, Ow);
        gemm_pure<1><<<dim3(16, 32, 1), 256, 0, stream>>>(Ow, wob, nullptr, out, nullptr);
    } else {
        u16* Qw  = (u16*)d_ws;
        u16* Vtd = (u16*)d_out;
        u16* Kw  = (u16*)d_out + NT;
        u16* Ow  = Qw;
        gemm_bt<0><<<dim3(16, 32, 2), 256, 0, stream>>>(x, wq, wk, Qw, Kw);
        gemm_bt<2><<<dim3(32, 16, 1), 256, 0, stream>>>(wv, x, nullptr, Vtd, nullptr);
        rope_kernel<<<dim3(4096, 2), 256, 0, stream>>>(Qw, Kw);
        attn_mfma<<<dim3(32, 16), 256, 0, stream>>>(Qw, Kw, Vtd, Ow);
        gemm_bt<1><<<dim3(16, 32, 1), 256, 0, stream>>>(Ow, wo, nullptr, out, nullptr);
    }
}